// Round 6
// baseline (174.206 us; speedup 1.0000x reference)
//
#include <hip/hip_runtime.h>
#include <hip/hip_bf16.h>

// Problem constants
#define B_    2
#define C_    256
#define T_    4096
#define GRP   32
#define CPG   8
#define NH    4
#define CH    64
#define K3C   768
#define SPLIT 4
#define GSL   8          // group-norm slices per group
#define NSTAT (B_ * GRP * GSL)   // 512
#define NCVT  128
#define LOG2E 1.4426950408889634f

typedef __attribute__((ext_vector_type(8))) short bf16x8;
typedef __attribute__((ext_vector_type(4))) float f32x4;
typedef __attribute__((ext_vector_type(16))) float f32x16;

#if __has_builtin(__builtin_amdgcn_exp2f)
#define EXP2(x) __builtin_amdgcn_exp2f(x)
#else
#define EXP2(x) exp2f(x)
#endif

__device__ __forceinline__ unsigned pk2(float a, float b) {
    __hip_bfloat162 h = __float22bfloat162_rn(make_float2(a, b));
    union { __hip_bfloat162 h2; unsigned u; } cv; cv.h2 = h;
    return cv.u;
}
__device__ __forceinline__ float bf2f(unsigned short u) {
    return __uint_as_float((unsigned)u << 16);
}

// Async global->LDS DMA, 16B per lane.  LDS dest = uniform base + lane*16.
__device__ __forceinline__ void gl_lds16(const unsigned short* g, unsigned short* l) {
    __builtin_amdgcn_global_load_lds(
        (const __attribute__((address_space(1))) unsigned int*)g,
        (__attribute__((address_space(3))) unsigned int*)l,
        16, 0, 0);
}

// ---------------------------------------------------------------------------
// Kernel 0: fused GroupNorm stats (blocks 0..511) + weight cvt (512..639).
// ---------------------------------------------------------------------------
__global__ __launch_bounds__(256) void pre_kernel(
    const float* __restrict__ x, float* __restrict__ stat,
    const float* __restrict__ qw, const float* __restrict__ pw,
    unsigned short* __restrict__ qwb, unsigned short* __restrict__ pwb) {
    int bid = blockIdx.x;
    int tid = threadIdx.x;
    if (bid < NSTAT) {
        int bg = bid >> 3, sl = bid & 7;
        const int SLN = CPG * T_ / GSL;        // 4096
        const float* xp = x + (size_t)bg * CPG * T_ + (size_t)sl * SLN;
        float s = 0.f, s2 = 0.f;
        for (int i = tid * 4; i < SLN; i += 1024) {
            float4 v = *(const float4*)&xp[i];
            s  += (v.x + v.y) + (v.z + v.w);
            s2 += (v.x * v.x + v.y * v.y) + (v.z * v.z + v.w * v.w);
        }
        for (int off = 32; off > 0; off >>= 1) {
            s  += __shfl_down(s,  off);
            s2 += __shfl_down(s2, off);
        }
        __shared__ float rs[4], rs2[4];
        int wid = tid >> 6;
        if ((tid & 63) == 0) { rs[wid] = s; rs2[wid] = s2; }
        __syncthreads();
        if (tid == 0) {
            stat[bid * 2]     = (rs[0] + rs[1]) + (rs[2] + rs[3]);
            stat[bid * 2 + 1] = (rs2[0] + rs2[1]) + (rs2[2] + rs2[3]);
        }
    } else {
        int i = (bid - NSTAT) * 256 + tid;
        const int n1 = K3C * C_ / 8;
        const float* src; unsigned short* dst;
        if (i < n1) { src = qw + 8 * i; dst = qwb + 8 * i; }
        else { int j = i - n1; src = pw + 8 * j; dst = pwb + 8 * j; }
        float4 a = *(const float4*)src;
        float4 b = *(const float4*)(src + 4);
        uint4 u;
        u.x = pk2(a.x, a.y); u.y = pk2(a.z, a.w);
        u.z = pk2(b.x, b.y); u.w = pk2(b.z, b.w);
        *(uint4*)dst = u;
    }
}

// ---------------------------------------------------------------------------
// Kernel 1: GroupNorm apply -> bf16 transposed xnT[b][t][c].
// ---------------------------------------------------------------------------
__global__ __launch_bounds__(256) void gn_apply_kernel(
    const float* __restrict__ x, const float* __restrict__ stat,
    const float* __restrict__ w, const float* __restrict__ b,
    unsigned short* __restrict__ xnT) {
    int bg = blockIdx.x, sl = blockIdx.y;
    int batch = bg / GRP, g = bg % GRP;
    const float* xp = x + (size_t)bg * CPG * T_;
    int tid = threadIdx.x;

    float s = 0.f, s2 = 0.f;
#pragma unroll
    for (int i = 0; i < GSL; ++i) {
        s  += stat[(bg * GSL + i) * 2];
        s2 += stat[(bg * GSL + i) * 2 + 1];
    }
    float inv_n = 1.f / (float)(CPG * T_);
    float mean = s * inv_n;
    float var  = s2 * inv_n - mean * mean;
    float inv  = rsqrtf(var + 1e-5f);

    float wv[8], bv[8];
#pragma unroll
    for (int j = 0; j < 8; j++) {
        float ww = w[g * CPG + j] * inv;
        wv[j] = ww;
        bv[j] = b[g * CPG + j] - mean * ww;
    }
    unsigned short* op = xnT + (size_t)batch * T_ * C_ + g * CPG;
    int t0 = sl * (T_ / GSL);
#pragma unroll
    for (int rep = 0; rep < 2; ++rep) {
        int t = t0 + rep * 256 + tid;
        float v[8];
#pragma unroll
        for (int j = 0; j < 8; j++) v[j] = xp[(size_t)j * T_ + t] * wv[j] + bv[j];
        uint4 u;
        u.x = pk2(v[0], v[1]); u.y = pk2(v[2], v[3]);
        u.z = pk2(v[4], v[5]); u.w = pk2(v[6], v[7]);
        *(uint4*)&op[(size_t)t * C_] = u;
    }
}

// ---------------------------------------------------------------------------
// Kernel 2: QKV GEMM.  W-tile staged in LDS once; X B-frags direct-global.
// grid(32,12,2), block 256.  Epilogue: q/k -> [t][c] (q pre-scaled), v -> v_d.
// ---------------------------------------------------------------------------
__global__ __launch_bounds__(256) void qkv_gemm_kernel(
    const unsigned short* __restrict__ Wb, const float* __restrict__ bias,
    const unsigned short* __restrict__ Xt, unsigned short* __restrict__ q_t,
    unsigned short* __restrict__ k_t, unsigned short* __restrict__ v_d) {
    int tb = blockIdx.x * 128;
    int by = blockIdx.y;
    int bz = blockIdx.z;
    int ob = by * 64;
    int tid = threadIdx.x;
    int l = tid & 15, oct = (tid >> 4) & 3, w = tid >> 6;

    __shared__ __align__(16) unsigned short SH[64 * 264];

#pragma unroll
    for (int j = 0; j < 8; ++j) {
        int idx = tid + 256 * j;
        int row = idx >> 5, ch = idx & 31;
        *(uint4*)&SH[row * 264 + ch * 8] =
            *(const uint4*)&Wb[(size_t)(ob + row) * C_ + ch * 8];
    }
    __syncthreads();

    const unsigned short* Xb = Xt + (size_t)bz * T_ * C_;

    f32x4 acc[4][2];
#pragma unroll
    for (int mf = 0; mf < 4; ++mf)
#pragma unroll
        for (int nf = 0; nf < 2; ++nf) acc[mf][nf] = (f32x4){0.f, 0.f, 0.f, 0.f};

#pragma unroll
    for (int kk = 0; kk < 8; ++kk) {
        int c0 = 32 * kk + 8 * oct;
        bf16x8 bfr[2];
#pragma unroll
        for (int nf = 0; nf < 2; ++nf)
            bfr[nf] = *(const bf16x8*)&Xb[(size_t)(tb + 32 * w + 16 * nf + l) * C_ + c0];
#pragma unroll
        for (int mf = 0; mf < 4; ++mf) {
            bf16x8 af = *(const bf16x8*)&SH[(16 * mf + l) * 264 + c0];
#pragma unroll
            for (int nf = 0; nf < 2; ++nf)
                acc[mf][nf] = __builtin_amdgcn_mfma_f32_16x16x32_bf16(af, bfr[nf], acc[mf][nf], 0, 0, 0);
        }
    }

    int head = by / 3, sec = by - 3 * head;
    int bh = bz * NH + head;

    if (sec < 2) {
        float scale = (sec == 0) ? 0.125f * LOG2E : 1.f;
        unsigned short* dst = ((sec == 0) ? q_t : k_t) + (size_t)bh * T_ * CH;
#pragma unroll
        for (int mf = 0; mf < 4; ++mf) {
            float bvs[4];
#pragma unroll
            for (int r = 0; r < 4; ++r) bvs[r] = bias[ob + 16 * mf + 4 * oct + r];
#pragma unroll
            for (int nf = 0; nf < 2; ++nf) {
                int t = tb + 32 * w + 16 * nf + l;
                float v0 = (acc[mf][nf][0] + bvs[0]) * scale;
                float v1 = (acc[mf][nf][1] + bvs[1]) * scale;
                float v2 = (acc[mf][nf][2] + bvs[2]) * scale;
                float v3 = (acc[mf][nf][3] + bvs[3]) * scale;
                uint2 u; u.x = pk2(v0, v1); u.y = pk2(v2, v3);
                *(uint2*)&dst[(size_t)t * CH + 16 * mf + 4 * oct] = u;
            }
        }
    } else {
        __syncthreads();   // reuse SH as Vl[64][136]
#pragma unroll
        for (int mf = 0; mf < 4; ++mf) {
            float bvs[4];
#pragma unroll
            for (int r = 0; r < 4; ++r) bvs[r] = bias[ob + 16 * mf + 4 * oct + r];
#pragma unroll
            for (int nf = 0; nf < 2; ++nf) {
                int tl = 32 * w + 16 * nf + l;
#pragma unroll
                for (int r = 0; r < 4; ++r) {
                    unsigned pv = pk2(acc[mf][nf][r] + bvs[r], 0.f);
                    SH[(16 * mf + 4 * oct + r) * 136 + tl] = (unsigned short)(pv & 0xffffu);
                }
            }
        }
        __syncthreads();
        unsigned short* vdst = v_d + (size_t)bh * CH * T_;
#pragma unroll
        for (int j = 0; j < 4; ++j) {
            int idx = tid + 256 * j;
            int row = idx >> 4, ch = idx & 15;
            *(uint4*)&vdst[(size_t)row * T_ + tb + ch * 8] =
                *(uint4*)&SH[row * 136 + ch * 8];
        }
    }
}

// ---------------------------------------------------------------------------
// Kernel 3: flash attention, 32x32x16 MFMA, in-register P transpose, and now:
//  - K fragments in REGISTERS with tile-ahead prefetch (each lane's frag is a
//    contiguous 16B global load; next tile's loads issued right after this
//    tile's QK MFMAs consume the regs -> ~700cy prefetch distance, drained by
//    the existing barrier).  Removes 8 of 16 LDS reads/tile + K staging.
//  - V stays in LDS (dbuf, global_load_lds) with EXTENDED swizzle
//    SW(row) = (row&7) ^ ((row>>3)&3): kills the 4-way bank conflict (lanes
//    li, li+8, li+16, li+24 shared row&7 -> same chunk -> same bank quad).
//  - QK split into S0-phase / exp(S0) / S1-phase / exp(S1) to cap VGPR peak
//    and overlap trans-pipe exp with MFMA.
// LDS = Vt[2] = 16KB.  grid 1024 = 4 blocks/CU exact fill.
// ---------------------------------------------------------------------------
__global__ __launch_bounds__(256, 4) void attn_kernel(
    const unsigned short* __restrict__ q_t, const unsigned short* __restrict__ k_t,
    const unsigned short* __restrict__ v_d, unsigned short* __restrict__ Opart,
    float* __restrict__ lbuf) {
    int bh = blockIdx.y;
    int sp = blockIdx.z;
    int t0 = blockIdx.x * 128;
    int tid = threadIdx.x;
    int ln = tid & 63;                    // lane in wave
    int li = ln & 31;                     // row/col within 32
    int hi = ln >> 5;                     // half-wave
    int w  = tid >> 6;                    // wave id 0..3
    int l7 = li & 7;
    int sw = l7 ^ ((li >> 3) & 3);        // extended swizzle (same for row li and 32+li)

    __shared__ __align__(16) unsigned short Vt[2][64 * 64];  // [c][s] swizzled

    const unsigned short* qb = q_t + (size_t)bh * T_ * CH;
    const unsigned short* kb = k_t + (size_t)bh * T_ * CH;
    const unsigned short* vb = v_d + (size_t)bh * CH * T_;

    // Q B-frags: col t = li, k(c) = 16*ks + 8*hi + j  (contiguous 16B)
    int tq = t0 + 32 * w + li;
    bf16x8 qf[4];
#pragma unroll
    for (int ks = 0; ks < 4; ++ks)
        qf[ks] = *(const bf16x8*)&qb[(size_t)tq * CH + ks * 16 + 8 * hi];

    // V staging lane addresses (extended swizzle; row r: content chunk =
    // sch ^ (r&7) ^ ((r>>3)&3); r&7 = rsub, r>>3 = 2w (+1 for second issue))
    int rsub = ln >> 3;                   // 0..7
    int sch  = ln & 7;
    int cm8_0 = (sch ^ rsub ^ ((2 * w) & 3)) * 8;
    int cm8_1 = (sch ^ rsub ^ ((2 * w + 1) & 3)) * 8;
    int vr0 = 16 * w + rsub;

#define STAGE_V(buf, s0) do {                                                      \
    gl_lds16(vb + (size_t)vr0 * T_ + (s0) + cm8_0,       &Vt[buf][(16 * w) * 64]);     \
    gl_lds16(vb + (size_t)(vr0 + 8) * T_ + (s0) + cm8_1, &Vt[buf][(16 * w + 8) * 64]); \
} while (0)

    f32x16 O0, O1;
#pragma unroll
    for (int i = 0; i < 16; ++i) { O0[i] = 0.f; O1[i] = 0.f; }
    float l_run = 0.f;

    int s_beg = sp * (T_ / SPLIT);
    const int NT = (T_ / SPLIT) / 64;     // 16 tiles

    // K A-frags in registers: lane reads rows (s0+li) / (s0+32+li), 16B at
    // col 16ks+8hi.  kp tracks the current tile base for this lane.
    const unsigned short* kp = kb + ((size_t)s_beg + li) * CH + 8 * hi;
    bf16x8 k0[4], k1[4];
#pragma unroll
    for (int ks = 0; ks < 4; ++ks) {
        k0[ks] = *(const bf16x8*)(kp + ks * 16);
        k1[ks] = *(const bf16x8*)(kp + 32 * CH + ks * 16);
    }

    STAGE_V(0, s_beg);
    __syncthreads();

    int cur = 0;
    for (int t = 0; t < NT; ++t) {
        int s0n = s_beg + (t + 1) * 64;
        bool more = (t + 1 < NT);
        if (more) STAGE_V(cur ^ 1, s0n);

        // ---- S0 = K[0:32]^T Q ----
        f32x16 S0;
#pragma unroll
        for (int i = 0; i < 16; ++i) S0[i] = 0.f;
        __builtin_amdgcn_s_setprio(1);
#pragma unroll
        for (int ks = 0; ks < 4; ++ks)
            S0 = __builtin_amdgcn_mfma_f32_32x32x16_bf16(k0[ks], qf[ks], S0, 0, 0, 0);
        __builtin_amdgcn_s_setprio(0);
        // prefetch next-tile K rows 0:32 (WAR after S0 MFMAs consumed k0)
        if (more) {
            const unsigned short* kpn = kp + 64 * CH;
#pragma unroll
            for (int ks = 0; ks < 4; ++ks)
                k0[ks] = *(const bf16x8*)(kpn + ks * 16);
        }

        // ---- p0 = exp2(S0) -> W0 (trans pipe overlaps next MFMAs) ----
        unsigned W0[8];
        float lloc = 0.f;
#pragma unroll
        for (int h = 0; h < 4; ++h) {
            float a0 = EXP2(S0[4 * h + 0]), a1 = EXP2(S0[4 * h + 1]);
            float a2 = EXP2(S0[4 * h + 2]), a3 = EXP2(S0[4 * h + 3]);
            lloc += (a0 + a1) + (a2 + a3);
            W0[2 * h] = pk2(a0, a1); W0[2 * h + 1] = pk2(a2, a3);
        }

        // ---- S1 = K[32:64]^T Q ----
        f32x16 S1;
#pragma unroll
        for (int i = 0; i < 16; ++i) S1[i] = 0.f;
        __builtin_amdgcn_s_setprio(1);
#pragma unroll
        for (int ks = 0; ks < 4; ++ks)
            S1 = __builtin_amdgcn_mfma_f32_32x32x16_bf16(k1[ks], qf[ks], S1, 0, 0, 0);
        __builtin_amdgcn_s_setprio(0);
        if (more) {
            const unsigned short* kpn = kp + 64 * CH;
#pragma unroll
            for (int ks = 0; ks < 4; ++ks)
                k1[ks] = *(const bf16x8*)(kpn + 32 * CH + ks * 16);
            kp = kpn;
        }

        // ---- p1 = exp2(S1) -> W1 ----
        unsigned W1[8];
#pragma unroll
        for (int h = 0; h < 4; ++h) {
            float b0 = EXP2(S1[4 * h + 0]), b1 = EXP2(S1[4 * h + 1]);
            float b2 = EXP2(S1[4 * h + 2]), b3 = EXP2(S1[4 * h + 3]);
            lloc += (b0 + b1) + (b2 + b3);
            W1[2 * h] = pk2(b0, b1); W1[2 * h + 1] = pk2(b2, b3);
        }
        l_run += lloc;

        // ---- O^T += V P^T; P B-frags built via permlane32_swap ----
        __builtin_amdgcn_s_setprio(1);
#pragma unroll
        for (int g = 0; g < 4; ++g) {
            int ks = g & 1;
            unsigned w0, w1, w2, w3;
            if (g < 2) {
                w0 = W0[4 * ks + 0]; w1 = W0[4 * ks + 1];
                w2 = W0[4 * ks + 2]; w3 = W0[4 * ks + 3];
            } else {
                w0 = W1[4 * ks + 0]; w1 = W1[4 * ks + 1];
                w2 = W1[4 * ks + 2]; w3 = W1[4 * ks + 3];
            }
            // dst'=[dst_lo|src_lo], src'=[dst_hi|src_hi]
            asm("v_permlane32_swap_b32 %0, %1" : "+v"(w0), "+v"(w2));
            asm("v_permlane32_swap_b32 %0, %1" : "+v"(w1), "+v"(w3));
            union { unsigned u[4]; bf16x8 v; } pu;
            pu.u[0] = w0; pu.u[1] = w1; pu.u[2] = w2; pu.u[3] = w3;
            bf16x8 va0 = *(const bf16x8*)
                &Vt[cur][li * 64 + (((2 * g + hi) ^ sw) * 8)];
            bf16x8 va1 = *(const bf16x8*)
                &Vt[cur][(32 + li) * 64 + (((2 * g + hi) ^ sw) * 8)];
            O0 = __builtin_amdgcn_mfma_f32_32x32x16_bf16(va0, pu.v, O0, 0, 0, 0);
            O1 = __builtin_amdgcn_mfma_f32_32x32x16_bf16(va1, pu.v, O1, 0, 0, 0);
        }
        __builtin_amdgcn_s_setprio(0);

        __syncthreads();   // V DMA + K prefetch drained; all waves done with cur
        cur ^= 1;
    }
#undef STAGE_V

    // ---- final l reduce + store normalized partials bf16 ----
    float lt = l_run + __shfl_xor(l_run, 32);
    float inv = 1.f / lt;
    size_t row = (size_t)(sp * 8 + bh) * T_ + tq;
    unsigned short* op = Opart + row * CH;
#pragma unroll
    for (int cb = 0; cb < 2; ++cb) {
#pragma unroll
        for (int h = 0; h < 4; ++h) {
            int c = 32 * cb + 8 * h + 4 * hi;
            float v0, v1, v2, v3;
            if (cb == 0) {
                v0 = O0[4 * h + 0]; v1 = O0[4 * h + 1];
                v2 = O0[4 * h + 2]; v3 = O0[4 * h + 3];
            } else {
                v0 = O1[4 * h + 0]; v1 = O1[4 * h + 1];
                v2 = O1[4 * h + 2]; v3 = O1[4 * h + 3];
            }
            uint2 u;
            u.x = pk2(v0 * inv, v1 * inv);
            u.y = pk2(v2 * inv, v3 * inv);
            *(uint2*)&op[c] = u;
        }
    }
    if (hi == 0) lbuf[row] = lt;
}

// ---------------------------------------------------------------------------
// Kernel 4: proj GEMM + FUSED combine + bias + residual -> fp32 out.
// (unchanged from R5)
// ---------------------------------------------------------------------------
__global__ __launch_bounds__(256) void proj_gemm_kernel(
    const unsigned short* __restrict__ Wb, const float* __restrict__ bias,
    const unsigned short* __restrict__ Opart, const float* __restrict__ lbuf,
    const float* __restrict__ xres, float* __restrict__ out) {
    int tb = blockIdx.x * 64;
    int ob = blockIdx.y * 64;
    int bz = blockIdx.z;
    int tid = threadIdx.x;
    int l = tid & 15, oct = (tid >> 4) & 3, w = tid >> 6;

    __shared__ __align__(16) unsigned short SH[64 * 264];

#pragma unroll
    for (int j = 0; j < 8; ++j) {
        int idx = tid + 256 * j;
        int row = idx >> 5, ch = idx & 31;
        *(uint4*)&SH[row * 264 + ch * 8] =
            *(const uint4*)&Wb[(size_t)(ob + row) * C_ + ch * 8];
    }
    __syncthreads();

    int t = tb + 16 * w + l;

    // normalized split weights per head (lane's t)
    float lwn[SPLIT][NH];
#pragma unroll
    for (int h = 0; h < NH; ++h) {
        float lw[SPLIT], lsum = 0.f;
#pragma unroll
        for (int sp = 0; sp < SPLIT; ++sp) {
            lw[sp] = lbuf[(size_t)(sp * 8 + bz * NH + h) * T_ + t];
            lsum += lw[sp];
        }
        float inv = 1.f / lsum;
#pragma unroll
        for (int sp = 0; sp < SPLIT; ++sp) lwn[sp][h] = lw[sp] * inv;
    }

    f32x4 acc[4];
#pragma unroll
    for (int mf = 0; mf < 4; ++mf) acc[mf] = (f32x4){0.f, 0.f, 0.f, 0.f};

#pragma unroll
    for (int kk = 0; kk < 8; ++kk) {
        int c0 = 32 * kk + 8 * oct;       // k-dim index into W (c-in 0..255)
        int h  = kk >> 1;                 // head owning this c-range
        int cc = 32 * (kk & 1) + 8 * oct; // c within head (0..63)

        // fused combine: weighted sum of SPLIT partials -> bf16x8 B-frag
        float o[8];
#pragma unroll
        for (int j = 0; j < 8; ++j) o[j] = 0.f;
#pragma unroll
        for (int sp = 0; sp < SPLIT; ++sp) {
            const unsigned short* p =
                Opart + ((size_t)(sp * 8 + bz * NH + h) * T_ + t) * CH + cc;
            uint4 u = *(const uint4*)p;
            float s = lwn[sp][h];
            o[0] += bf2f((unsigned short)(u.x & 0xffffu)) * s;
            o[1] += bf2f((unsigned short)(u.x >> 16)) * s;
            o[2] += bf2f((unsigned short)(u.y & 0xffffu)) * s;
            o[3] += bf2f((unsigned short)(u.y >> 16)) * s;
            o[4] += bf2f((unsigned short)(u.z & 0xffffu)) * s;
            o[5] += bf2f((unsigned short)(u.z >> 16)) * s;
            o[6] += bf2f((unsigned short)(u.w & 0xffffu)) * s;
            o[7] += bf2f((unsigned short)(u.w >> 16)) * s;
        }
        union { uint4 u; bf16x8 v; } pb;
        pb.u.x = pk2(o[0], o[1]); pb.u.y = pk2(o[2], o[3]);
        pb.u.z = pk2(o[4], o[5]); pb.u.w = pk2(o[6], o[7]);

#pragma unroll
        for (int mf = 0; mf < 4; ++mf) {
            bf16x8 af = *(const bf16x8*)&SH[(16 * mf + l) * 264 + c0];
            acc[mf] = __builtin_amdgcn_mfma_f32_16x16x32_bf16(af, pb.v, acc[mf], 0, 0, 0);
        }
    }

#pragma unroll
    for (int mf = 0; mf < 4; ++mf) {
#pragma unroll
        for (int r = 0; r < 4; ++r) {
            int o = ob + 16 * mf + 4 * oct + r;
            size_t idx = ((size_t)bz * C_ + o) * T_ + t;
            out[idx] = acc[mf][r] + bias[o] + xres[idx];
        }
    }
}

// ---------------------------------------------------------------------------
extern "C" void kernel_launch(void* const* d_in, const int* in_sizes, int n_in,
                              void* d_out, int out_size, void* d_ws, size_t ws_size,
                              hipStream_t stream) {
    const float* x      = (const float*)d_in[0];
    const float* norm_w = (const float*)d_in[1];
    const float* norm_b = (const float*)d_in[2];
    const float* qkv_w  = (const float*)d_in[3];
    const float* qkv_b  = (const float*)d_in[4];
    const float* proj_w = (const float*)d_in[5];
    const float* proj_b = (const float*)d_in[6];
    float* out = (float*)d_out;

    char* p = (char*)d_ws;
    unsigned short* xnT = (unsigned short*)p; p += (size_t)B_ * T_ * C_ * 2;        // 4 MB
    unsigned short* qwb = (unsigned short*)p; p += (size_t)K3C * C_ * 2;            // 384 KB
    unsigned short* pwb = (unsigned short*)p; p += (size_t)C_ * C_ * 2;             // 128 KB
    unsigned short* q_t = (unsigned short*)p; p += (size_t)B_ * NH * T_ * CH * 2;   // 4 MB
    unsigned short* k_t = (unsigned short*)p; p += (size_t)B_ * NH * T_ * CH * 2;   // 4 MB
    unsigned short* v_d = (unsigned short*)p; p += (size_t)B_ * NH * T_ * CH * 2;   // 4 MB
    unsigned short* Opart = (unsigned short*)p; p += (size_t)SPLIT * 8 * T_ * CH * 2; // 16 MB
    float* lbuf         = (float*)p;          p += (size_t)SPLIT * 8 * T_ * 4;      // 512 KB
    float* stat         = (float*)p;          p += (size_t)NSTAT * 2 * 4;           // 4 KB

    pre_kernel<<<dim3(NSTAT + NCVT), dim3(256), 0, stream>>>(
        x, stat, qkv_w, proj_w, qwb, pwb);
    gn_apply_kernel<<<dim3(B_ * GRP, GSL), dim3(256), 0, stream>>>(
        x, stat, norm_w, norm_b, xnT);
    qkv_gemm_kernel<<<dim3(T_ / 128, 12, B_), dim3(256), 0, stream>>>(
        qwb, qkv_b, xnT, q_t, k_t, v_d);
    attn_kernel<<<dim3(T_ / 128, B_ * NH, SPLIT), dim3(256), 0, stream>>>(
        q_t, k_t, v_d, Opart, lbuf);
    proj_gemm_kernel<<<dim3(T_ / 64, C_ / 64, B_), dim3(256), 0, stream>>>(
        pwb, proj_b, Opart, lbuf, x, out);
}

// Round 7
// 135.540 us; speedup vs baseline: 1.2853x; 1.2853x over previous
//
#include <hip/hip_runtime.h>
#include <hip/hip_bf16.h>

// Problem constants
#define B_    2
#define C_    256
#define T_    4096
#define GRP   32
#define CPG   8
#define NH    4
#define CH    64
#define K3C   768
#define SPLIT 4
#define GSL   8          // group-norm slices per group
#define NSTAT (B_ * GRP * GSL)   // 512
#define NCVT  128
#define LOG2E 1.4426950408889634f

typedef __attribute__((ext_vector_type(8))) short bf16x8;
typedef __attribute__((ext_vector_type(4))) float f32x4;
typedef __attribute__((ext_vector_type(16))) float f32x16;

#if __has_builtin(__builtin_amdgcn_exp2f)
#define EXP2(x) __builtin_amdgcn_exp2f(x)
#else
#define EXP2(x) exp2f(x)
#endif

__device__ __forceinline__ unsigned pk2(float a, float b) {
    __hip_bfloat162 h = __float22bfloat162_rn(make_float2(a, b));
    union { __hip_bfloat162 h2; unsigned u; } cv; cv.h2 = h;
    return cv.u;
}
__device__ __forceinline__ float bf2f(unsigned short u) {
    return __uint_as_float((unsigned)u << 16);
}

// Async global->LDS DMA, 16B per lane.  LDS dest = uniform base + lane*16.
__device__ __forceinline__ void gl_lds16(const unsigned short* g, unsigned short* l) {
    __builtin_amdgcn_global_load_lds(
        (const __attribute__((address_space(1))) unsigned int*)g,
        (__attribute__((address_space(3))) unsigned int*)l,
        16, 0, 0);
}

// Tiled layouts (coalescing fix, R7):
//   xnT  : elem offset = ((b*256 + (t>>4))*32 + (c>>3))*128 + (t&15)*8 + (c&7)
//   Opart: elem offset = ((spbh*256 + (t>>4))*8 + (c>>3))*128 + (t&15)*8 + (c&7)
// Lane-consecutive t at fixed c-chunk -> contiguous 16B per lane.

// ---------------------------------------------------------------------------
// Kernel 0: fused GroupNorm stats (blocks 0..511) + weight cvt (512..639).
// ---------------------------------------------------------------------------
__global__ __launch_bounds__(256) void pre_kernel(
    const float* __restrict__ x, float* __restrict__ stat,
    const float* __restrict__ qw, const float* __restrict__ pw,
    unsigned short* __restrict__ qwb, unsigned short* __restrict__ pwb) {
    int bid = blockIdx.x;
    int tid = threadIdx.x;
    if (bid < NSTAT) {
        int bg = bid >> 3, sl = bid & 7;
        const int SLN = CPG * T_ / GSL;        // 4096
        const float* xp = x + (size_t)bg * CPG * T_ + (size_t)sl * SLN;
        float s = 0.f, s2 = 0.f;
        for (int i = tid * 4; i < SLN; i += 1024) {
            float4 v = *(const float4*)&xp[i];
            s  += (v.x + v.y) + (v.z + v.w);
            s2 += (v.x * v.x + v.y * v.y) + (v.z * v.z + v.w * v.w);
        }
        for (int off = 32; off > 0; off >>= 1) {
            s  += __shfl_down(s,  off);
            s2 += __shfl_down(s2, off);
        }
        __shared__ float rs[4], rs2[4];
        int wid = tid >> 6;
        if ((tid & 63) == 0) { rs[wid] = s; rs2[wid] = s2; }
        __syncthreads();
        if (tid == 0) {
            stat[bid * 2]     = (rs[0] + rs[1]) + (rs[2] + rs[3]);
            stat[bid * 2 + 1] = (rs2[0] + rs2[1]) + (rs2[2] + rs2[3]);
        }
    } else {
        int i = (bid - NSTAT) * 256 + tid;
        const int n1 = K3C * C_ / 8;
        const float* src; unsigned short* dst;
        if (i < n1) { src = qw + 8 * i; dst = qwb + 8 * i; }
        else { int j = i - n1; src = pw + 8 * j; dst = pwb + 8 * j; }
        float4 a = *(const float4*)src;
        float4 b = *(const float4*)(src + 4);
        uint4 u;
        u.x = pk2(a.x, a.y); u.y = pk2(a.z, a.w);
        u.z = pk2(b.x, b.y); u.w = pk2(b.z, b.w);
        *(uint4*)dst = u;
    }
}

// ---------------------------------------------------------------------------
// Kernel 1: GroupNorm apply -> bf16 TILED xnT (coalesced 256B-run writes).
// ---------------------------------------------------------------------------
__global__ __launch_bounds__(256) void gn_apply_kernel(
    const float* __restrict__ x, const float* __restrict__ stat,
    const float* __restrict__ w, const float* __restrict__ b,
    unsigned short* __restrict__ xnT) {
    int bg = blockIdx.x, sl = blockIdx.y;
    int batch = bg / GRP, g = bg % GRP;
    const float* xp = x + (size_t)bg * CPG * T_;
    int tid = threadIdx.x;

    float s = 0.f, s2 = 0.f;
#pragma unroll
    for (int i = 0; i < GSL; ++i) {
        s  += stat[(bg * GSL + i) * 2];
        s2 += stat[(bg * GSL + i) * 2 + 1];
    }
    float inv_n = 1.f / (float)(CPG * T_);
    float mean = s * inv_n;
    float var  = s2 * inv_n - mean * mean;
    float inv  = rsqrtf(var + 1e-5f);

    float wv[8], bv[8];
#pragma unroll
    for (int j = 0; j < 8; j++) {
        float ww = w[g * CPG + j] * inv;
        wv[j] = ww;
        bv[j] = b[g * CPG + j] - mean * ww;
    }
    int t0 = sl * (T_ / GSL);
#pragma unroll
    for (int rep = 0; rep < 2; ++rep) {
        int t = t0 + rep * 256 + tid;
        float v[8];
#pragma unroll
        for (int j = 0; j < 8; j++) v[j] = xp[(size_t)j * T_ + t] * wv[j] + bv[j];
        uint4 u;
        u.x = pk2(v[0], v[1]); u.y = pk2(v[2], v[3]);
        u.z = pk2(v[4], v[5]); u.w = pk2(v[6], v[7]);
        *(uint4*)&xnT[(((size_t)batch * 256 + (t >> 4)) * 32 + g) * 128
                      + (t & 15) * 8] = u;
    }
}

// ---------------------------------------------------------------------------
// Kernel 2: QKV GEMM.  W-tile in LDS; X B-frags from TILED xnT -> each wave
// load is a fully contiguous 1KB (lanes l:+16B, oct:+256B).  grid(32,12,2).
// ---------------------------------------------------------------------------
__global__ __launch_bounds__(256) void qkv_gemm_kernel(
    const unsigned short* __restrict__ Wb, const float* __restrict__ bias,
    const unsigned short* __restrict__ Xt, unsigned short* __restrict__ q_t,
    unsigned short* __restrict__ k_t, unsigned short* __restrict__ v_d) {
    int tb = blockIdx.x * 128;
    int by = blockIdx.y;
    int bz = blockIdx.z;
    int ob = by * 64;
    int tid = threadIdx.x;
    int l = tid & 15, oct = (tid >> 4) & 3, w = tid >> 6;

    __shared__ __align__(16) unsigned short SH[64 * 264];

#pragma unroll
    for (int j = 0; j < 8; ++j) {
        int idx = tid + 256 * j;
        int row = idx >> 5, ch = idx & 31;
        *(uint4*)&SH[row * 264 + ch * 8] =
            *(const uint4*)&Wb[(size_t)(ob + row) * C_ + ch * 8];
    }
    __syncthreads();

    f32x4 acc[4][2];
#pragma unroll
    for (int mf = 0; mf < 4; ++mf)
#pragma unroll
        for (int nf = 0; nf < 2; ++nf) acc[mf][nf] = (f32x4){0.f, 0.f, 0.f, 0.f};

#pragma unroll
    for (int kk = 0; kk < 8; ++kk) {
        int c0 = 32 * kk + 8 * oct;
        bf16x8 bfr[2];
#pragma unroll
        for (int nf = 0; nf < 2; ++nf)
            bfr[nf] = *(const bf16x8*)
                &Xt[(((size_t)bz * 256 + (tb >> 4) + 2 * w + nf) * 32
                     + 4 * kk + oct) * 128 + l * 8];
#pragma unroll
        for (int mf = 0; mf < 4; ++mf) {
            bf16x8 af = *(const bf16x8*)&SH[(16 * mf + l) * 264 + c0];
#pragma unroll
            for (int nf = 0; nf < 2; ++nf)
                acc[mf][nf] = __builtin_amdgcn_mfma_f32_16x16x32_bf16(af, bfr[nf], acc[mf][nf], 0, 0, 0);
        }
    }

    int head = by / 3, sec = by - 3 * head;
    int bh = bz * NH + head;

    if (sec < 2) {
        float scale = (sec == 0) ? 0.125f * LOG2E : 1.f;
        unsigned short* dst = ((sec == 0) ? q_t : k_t) + (size_t)bh * T_ * CH;
#pragma unroll
        for (int mf = 0; mf < 4; ++mf) {
            float bvs[4];
#pragma unroll
            for (int r = 0; r < 4; ++r) bvs[r] = bias[ob + 16 * mf + 4 * oct + r];
#pragma unroll
            for (int nf = 0; nf < 2; ++nf) {
                int t = tb + 32 * w + 16 * nf + l;
                float v0 = (acc[mf][nf][0] + bvs[0]) * scale;
                float v1 = (acc[mf][nf][1] + bvs[1]) * scale;
                float v2 = (acc[mf][nf][2] + bvs[2]) * scale;
                float v3 = (acc[mf][nf][3] + bvs[3]) * scale;
                uint2 u; u.x = pk2(v0, v1); u.y = pk2(v2, v3);
                *(uint2*)&dst[(size_t)t * CH + 16 * mf + 4 * oct] = u;
            }
        }
    } else {
        __syncthreads();   // reuse SH as Vl[64][136]
#pragma unroll
        for (int mf = 0; mf < 4; ++mf) {
            float bvs[4];
#pragma unroll
            for (int r = 0; r < 4; ++r) bvs[r] = bias[ob + 16 * mf + 4 * oct + r];
#pragma unroll
            for (int nf = 0; nf < 2; ++nf) {
                int tl = 32 * w + 16 * nf + l;
#pragma unroll
                for (int r = 0; r < 4; ++r) {
                    unsigned pv = pk2(acc[mf][nf][r] + bvs[r], 0.f);
                    SH[(16 * mf + 4 * oct + r) * 136 + tl] = (unsigned short)(pv & 0xffffu);
                }
            }
        }
        __syncthreads();
        unsigned short* vdst = v_d + (size_t)bh * CH * T_;
#pragma unroll
        for (int j = 0; j < 4; ++j) {
            int idx = tid + 256 * j;
            int row = idx >> 4, ch = idx & 15;
            *(uint4*)&vdst[(size_t)row * T_ + tb + ch * 8] =
                *(uint4*)&SH[row * 136 + ch * 8];
        }
    }
}

// ---------------------------------------------------------------------------
// Kernel 3: flash attention, 32x32x16 MFMA, in-register P transpose.
// K AND V in LDS (dbuf, global_load_lds, single barrier/tile) with EXTENDED
// swizzle SW(r) = (r&7) ^ ((r>>3)&3) -> 0 bank conflicts (R6-validated).
// Opart written in TILED layout (coalesced).  32KB LDS, 4 blocks/CU exact.
// ---------------------------------------------------------------------------
__global__ __launch_bounds__(256, 4) void attn_kernel(
    const unsigned short* __restrict__ q_t, const unsigned short* __restrict__ k_t,
    const unsigned short* __restrict__ v_d, unsigned short* __restrict__ Opart,
    float* __restrict__ lbuf) {
    int bh = blockIdx.y;
    int sp = blockIdx.z;
    int t0 = blockIdx.x * 128;
    int tid = threadIdx.x;
    int ln = tid & 63;                    // lane in wave
    int li = ln & 31;                     // row/col within 32
    int hi = ln >> 5;                     // half-wave
    int w  = tid >> 6;                    // wave id 0..3
    int l7 = li & 7;
    int sw = l7 ^ ((li >> 3) & 3);        // SW(li) == SW(32+li)

    __shared__ __align__(16) unsigned short Kt[2][64 * 64];  // [s][c] ext-swizzled
    __shared__ __align__(16) unsigned short Vt[2][64 * 64];  // [c][s] ext-swizzled

    const unsigned short* qb = q_t + (size_t)bh * T_ * CH;
    const unsigned short* kb = k_t + (size_t)bh * T_ * CH;
    const unsigned short* vb = v_d + (size_t)bh * CH * T_;

    // Q B-frags: col t = li, k(c) = 16*ks + 8*hi + j  (contiguous 16B)
    int tq = t0 + 32 * w + li;
    bf16x8 qf[4];
#pragma unroll
    for (int ks = 0; ks < 4; ++ks)
        qf[ks] = *(const bf16x8*)&qb[(size_t)tq * CH + ks * 16 + 8 * hi];

    // staging: wave w stages rows [16w,16w+8) then [16w+8,16w+16) of each
    // 64-row tile; lane ln: sub-row rsub = ln>>3, phys chunk sch = ln&7;
    // source content chunk = sch ^ SW(row); row>>3 = 2w (issue0) / 2w+1 (issue1)
    int rsub = ln >> 3;
    int sch  = ln & 7;
    int cm8_0 = (sch ^ rsub ^ ((2 * w) & 3)) * 8;
    int cm8_1 = (sch ^ rsub ^ ((2 * w + 1) & 3)) * 8;
    int kr0 = 16 * w + rsub;

#define STAGE(buf, s0) do {                                                            \
    gl_lds16(kb + (size_t)((s0) + kr0) * CH + cm8_0,     &Kt[buf][(16 * w) * 64]);     \
    gl_lds16(kb + (size_t)((s0) + kr0 + 8) * CH + cm8_1, &Kt[buf][(16 * w + 8) * 64]); \
    gl_lds16(vb + (size_t)kr0 * T_ + (s0) + cm8_0,       &Vt[buf][(16 * w) * 64]);     \
    gl_lds16(vb + (size_t)(kr0 + 8) * T_ + (s0) + cm8_1, &Vt[buf][(16 * w + 8) * 64]); \
} while (0)

    f32x16 O0, O1;
#pragma unroll
    for (int i = 0; i < 16; ++i) { O0[i] = 0.f; O1[i] = 0.f; }
    float l_run = 0.f;

    int s_beg = sp * (T_ / SPLIT);
    const int NT = (T_ / SPLIT) / 64;     // 16 tiles

    STAGE(0, s_beg);
    __syncthreads();

    int cur = 0;
    for (int t = 0; t < NT; ++t) {
        if (t + 1 < NT) STAGE(cur ^ 1, s_beg + (t + 1) * 64);

        // ---- S^T = K^T Q (2 s-blocks of 32) ----
        f32x16 S0, S1;
#pragma unroll
        for (int i = 0; i < 16; ++i) { S0[i] = 0.f; S1[i] = 0.f; }
        __builtin_amdgcn_s_setprio(1);
#pragma unroll
        for (int ks = 0; ks < 4; ++ks) {
            bf16x8 ka0 = *(const bf16x8*)
                &Kt[cur][li * 64 + (((2 * ks + hi) ^ sw) * 8)];
            bf16x8 ka1 = *(const bf16x8*)
                &Kt[cur][(32 + li) * 64 + (((2 * ks + hi) ^ sw) * 8)];
            S0 = __builtin_amdgcn_mfma_f32_32x32x16_bf16(ka0, qf[ks], S0, 0, 0, 0);
            S1 = __builtin_amdgcn_mfma_f32_32x32x16_bf16(ka1, qf[ks], S1, 0, 0, 0);
        }
        __builtin_amdgcn_s_setprio(0);

        // ---- p = exp2(S) -> bf16 pairs; lane-local l partial ----
        unsigned W0[8], W1[8];
        float lloc = 0.f;
#pragma unroll
        for (int h = 0; h < 4; ++h) {
            float a0 = EXP2(S0[4 * h + 0]), a1 = EXP2(S0[4 * h + 1]);
            float a2 = EXP2(S0[4 * h + 2]), a3 = EXP2(S0[4 * h + 3]);
            float b0 = EXP2(S1[4 * h + 0]), b1 = EXP2(S1[4 * h + 1]);
            float b2 = EXP2(S1[4 * h + 2]), b3 = EXP2(S1[4 * h + 3]);
            lloc += ((a0 + a1) + (a2 + a3)) + ((b0 + b1) + (b2 + b3));
            W0[2 * h] = pk2(a0, a1); W0[2 * h + 1] = pk2(a2, a3);
            W1[2 * h] = pk2(b0, b1); W1[2 * h + 1] = pk2(b2, b3);
        }
        l_run += lloc;

        // ---- O^T += V P^T; P B-frags built via permlane32_swap ----
        __builtin_amdgcn_s_setprio(1);
#pragma unroll
        for (int g = 0; g < 4; ++g) {
            int ks = g & 1;
            unsigned w0, w1, w2, w3;
            if (g < 2) {
                w0 = W0[4 * ks + 0]; w1 = W0[4 * ks + 1];
                w2 = W0[4 * ks + 2]; w3 = W0[4 * ks + 3];
            } else {
                w0 = W1[4 * ks + 0]; w1 = W1[4 * ks + 1];
                w2 = W1[4 * ks + 2]; w3 = W1[4 * ks + 3];
            }
            // dst'=[dst_lo|src_lo], src'=[dst_hi|src_hi]
            asm("v_permlane32_swap_b32 %0, %1" : "+v"(w0), "+v"(w2));
            asm("v_permlane32_swap_b32 %0, %1" : "+v"(w1), "+v"(w3));
            union { unsigned u[4]; bf16x8 v; } pu;
            pu.u[0] = w0; pu.u[1] = w1; pu.u[2] = w2; pu.u[3] = w3;
            bf16x8 va0 = *(const bf16x8*)
                &Vt[cur][li * 64 + (((2 * g + hi) ^ sw) * 8)];
            bf16x8 va1 = *(const bf16x8*)
                &Vt[cur][(32 + li) * 64 + (((2 * g + hi) ^ sw) * 8)];
            O0 = __builtin_amdgcn_mfma_f32_32x32x16_bf16(va0, pu.v, O0, 0, 0, 0);
            O1 = __builtin_amdgcn_mfma_f32_32x32x16_bf16(va1, pu.v, O1, 0, 0, 0);
        }
        __builtin_amdgcn_s_setprio(0);

        __syncthreads();   // staged loads drained + all waves done with cur
        cur ^= 1;
    }
#undef STAGE

    // ---- final l reduce + store normalized partials bf16 (TILED Opart) ----
    float lt = l_run + __shfl_xor(l_run, 32);
    float inv = 1.f / lt;
    size_t obase = ((size_t)(sp * 8 + bh) * 256 + (tq >> 4)) * 8;
    int ti = tq & 15;
#pragma unroll
    for (int cb = 0; cb < 2; ++cb) {
#pragma unroll
        for (int h = 0; h < 4; ++h) {
            float v0, v1, v2, v3;
            if (cb == 0) {
                v0 = O0[4 * h + 0]; v1 = O0[4 * h + 1];
                v2 = O0[4 * h + 2]; v3 = O0[4 * h + 3];
            } else {
                v0 = O1[4 * h + 0]; v1 = O1[4 * h + 1];
                v2 = O1[4 * h + 2]; v3 = O1[4 * h + 3];
            }
            uint2 u;
            u.x = pk2(v0 * inv, v1 * inv);
            u.y = pk2(v2 * inv, v3 * inv);
            *(uint2*)&Opart[(obase + 4 * cb + h) * 128 + ti * 8 + 4 * hi] = u;
        }
    }
    if (hi == 0) lbuf[(size_t)(sp * 8 + bh) * T_ + tq] = lt;
}

// ---------------------------------------------------------------------------
// Kernel 4: proj GEMM + FUSED combine + bias + residual -> fp32 out.
// Opart read from TILED layout -> contiguous 1KB per wave instruction.
// ---------------------------------------------------------------------------
__global__ __launch_bounds__(256) void proj_gemm_kernel(
    const unsigned short* __restrict__ Wb, const float* __restrict__ bias,
    const unsigned short* __restrict__ Opart, const float* __restrict__ lbuf,
    const float* __restrict__ xres, float* __restrict__ out) {
    int tb = blockIdx.x * 64;
    int ob = blockIdx.y * 64;
    int bz = blockIdx.z;
    int tid = threadIdx.x;
    int l = tid & 15, oct = (tid >> 4) & 3, w = tid >> 6;

    __shared__ __align__(16) unsigned short SH[64 * 264];

#pragma unroll
    for (int j = 0; j < 8; ++j) {
        int idx = tid + 256 * j;
        int row = idx >> 5, ch = idx & 31;
        *(uint4*)&SH[row * 264 + ch * 8] =
            *(const uint4*)&Wb[(size_t)(ob + row) * C_ + ch * 8];
    }
    __syncthreads();

    int t = tb + 16 * w + l;

    // normalized split weights per head (lane's t)
    float lwn[SPLIT][NH];
#pragma unroll
    for (int h = 0; h < NH; ++h) {
        float lw[SPLIT], lsum = 0.f;
#pragma unroll
        for (int sp = 0; sp < SPLIT; ++sp) {
            lw[sp] = lbuf[(size_t)(sp * 8 + bz * NH + h) * T_ + t];
            lsum += lw[sp];
        }
        float inv = 1.f / lsum;
#pragma unroll
        for (int sp = 0; sp < SPLIT; ++sp) lwn[sp][h] = lw[sp] * inv;
    }

    f32x4 acc[4];
#pragma unroll
    for (int mf = 0; mf < 4; ++mf) acc[mf] = (f32x4){0.f, 0.f, 0.f, 0.f};

#pragma unroll
    for (int kk = 0; kk < 8; ++kk) {
        int c0 = 32 * kk + 8 * oct;       // k-dim index into W (c-in 0..255)
        int h  = kk >> 1;                 // head owning this c-range
        int cc = 4 * (kk & 1) + oct;      // 16B chunk within head (0..7)

        // fused combine: weighted sum of SPLIT partials -> bf16x8 B-frag
        float o[8];
#pragma unroll
        for (int j = 0; j < 8; ++j) o[j] = 0.f;
#pragma unroll
        for (int sp = 0; sp < SPLIT; ++sp) {
            const unsigned short* p = Opart +
                (((size_t)(sp * 8 + bz * NH + h) * 256 + (t >> 4)) * 8 + cc) * 128
                + (t & 15) * 8;
            uint4 u = *(const uint4*)p;
            float s = lwn[sp][h];
            o[0] += bf2f((unsigned short)(u.x & 0xffffu)) * s;
            o[1] += bf2f((unsigned short)(u.x >> 16)) * s;
            o[2] += bf2f((unsigned short)(u.y & 0xffffu)) * s;
            o[3] += bf2f((unsigned short)(u.y >> 16)) * s;
            o[4] += bf2f((unsigned short)(u.z & 0xffffu)) * s;
            o[5] += bf2f((unsigned short)(u.z >> 16)) * s;
            o[6] += bf2f((unsigned short)(u.w & 0xffffu)) * s;
            o[7] += bf2f((unsigned short)(u.w >> 16)) * s;
        }
        union { uint4 u; bf16x8 v; } pb;
        pb.u.x = pk2(o[0], o[1]); pb.u.y = pk2(o[2], o[3]);
        pb.u.z = pk2(o[4], o[5]); pb.u.w = pk2(o[6], o[7]);

#pragma unroll
        for (int mf = 0; mf < 4; ++mf) {
            bf16x8 af = *(const bf16x8*)&SH[(16 * mf + l) * 264 + c0];
            acc[mf] = __builtin_amdgcn_mfma_f32_16x16x32_bf16(af, pb.v, acc[mf], 0, 0, 0);
        }
    }

#pragma unroll
    for (int mf = 0; mf < 4; ++mf) {
#pragma unroll
        for (int r = 0; r < 4; ++r) {
            int o = ob + 16 * mf + 4 * oct + r;
            size_t idx = ((size_t)bz * C_ + o) * T_ + t;
            out[idx] = acc[mf][r] + bias[o] + xres[idx];
        }
    }
}

// ---------------------------------------------------------------------------
extern "C" void kernel_launch(void* const* d_in, const int* in_sizes, int n_in,
                              void* d_out, int out_size, void* d_ws, size_t ws_size,
                              hipStream_t stream) {
    const float* x      = (const float*)d_in[0];
    const float* norm_w = (const float*)d_in[1];
    const float* norm_b = (const float*)d_in[2];
    const float* qkv_w  = (const float*)d_in[3];
    const float* qkv_b  = (const float*)d_in[4];
    const float* proj_w = (const float*)d_in[5];
    const float* proj_b = (const float*)d_in[6];
    float* out = (float*)d_out;

    char* p = (char*)d_ws;
    unsigned short* xnT = (unsigned short*)p; p += (size_t)B_ * T_ * C_ * 2;        // 4 MB
    unsigned short* qwb = (unsigned short*)p; p += (size_t)K3C * C_ * 2;            // 384 KB
    unsigned short* pwb = (unsigned short*)p; p += (size_t)C_ * C_ * 2;             // 128 KB
    unsigned short* q_t = (unsigned short*)p; p += (size_t)B_ * NH * T_ * CH * 2;   // 4 MB
    unsigned short* k_t = (unsigned short*)p; p += (size_t)B_ * NH * T_ * CH * 2;   // 4 MB
    unsigned short* v_d = (unsigned short*)p; p += (size_t)B_ * NH * T_ * CH * 2;   // 4 MB
    unsigned short* Opart = (unsigned short*)p; p += (size_t)SPLIT * 8 * T_ * CH * 2; // 16 MB
    float* lbuf         = (float*)p;          p += (size_t)SPLIT * 8 * T_ * 4;      // 512 KB
    float* stat         = (float*)p;          p += (size_t)NSTAT * 2 * 4;           // 4 KB

    pre_kernel<<<dim3(NSTAT + NCVT), dim3(256), 0, stream>>>(
        x, stat, qkv_w, proj_w, qwb, pwb);
    gn_apply_kernel<<<dim3(B_ * GRP, GSL), dim3(256), 0, stream>>>(
        x, stat, norm_w, norm_b, xnT);
    qkv_gemm_kernel<<<dim3(T_ / 128, 12, B_), dim3(256), 0, stream>>>(
        qwb, qkv_b, xnT, q_t, k_t, v_d);
    attn_kernel<<<dim3(T_ / 128, B_ * NH, SPLIT), dim3(256), 0, stream>>>(
        q_t, k_t, v_d, Opart, lbuf);
    proj_gemm_kernel<<<dim3(T_ / 64, C_ / 64, B_), dim3(256), 0, stream>>>(
        pwb, proj_b, Opart, lbuf, x, out);
}